// Round 14
// baseline (305.304 us; speedup 1.0000x reference)
//
#include <hip/hip_runtime.h>
#include <math.h>

// ---------------------------------------------------------------------------
// Problem constants (bs=256, in_feat=48, d_model=512, dct_n=10, input_n=50,
// output_n=25, KERNEL=10, HEADS=4, vl=35, vn=16)
// ---------------------------------------------------------------------------
static constexpr float BN_SCALE_F = 0.9999950000374997f;

typedef __bf16 bf16;
typedef bf16 bf16x8 __attribute__((ext_vector_type(8)));
typedef bf16 bf16x4 __attribute__((ext_vector_type(4)));
typedef float floatx4 __attribute__((ext_vector_type(4)));

#define GLOBAL_AS __attribute__((address_space(1)))
#define LDS_AS __attribute__((address_space(3)))

__device__ __forceinline__ float tanh_fast(float x) {
    const float e = __expf(2.f * x);
    return 1.f - 2.f / (e + 1.f);
}

// ---------------- slim prep: only what conv1 needs (1883 blocks) -------------
__global__ __launch_bounds__(256) void k_prep(
    const float* __restrict__ src, const float* __restrict__ cq1,
    const float* __restrict__ ck1, float* __restrict__ dct10,
    bf16* __restrict__ srcbf, bf16* __restrict__ w1tq, bf16* __restrict__ w1tk) {
    int bb = blockIdx.x;
    const int t = threadIdx.x;
    if (bb < 2) {
        int id = bb * 256 + t;
        if (id < 350) {
            int k = id / 35, i = id % 35;
            double w = (k == 0) ? sqrt(1.0 / 35.0) : sqrt(2.0 / 35.0);
            dct10[id] = (float)(w * cos(3.14159265358979323846 * (i + 0.5) * k / 35.0));
        }
        return;
    }
    bb -= 2;
    if (bb < 601) {
        // srcbf: float4 -> bf16x4, 4 elems/thread (tail zero-padded)
        const int id4 = (bb * 256 + t) * 4;
        if (id4 + 3 < 614400) {
            const float4 v = *(const float4*)(src + id4);
            bf16x4 ov;
            ov[0] = (bf16)v.x; ov[1] = (bf16)v.y;
            ov[2] = (bf16)v.z; ov[3] = (bf16)v.w;
            *(bf16x4*)(srcbf + id4) = ov;
        } else if (id4 < 614656) {
#pragma unroll
            for (int j = 0; j < 4; ++j) {
                const int id = id4 + j;
                if (id < 614656) srcbf[id] = (bf16)(id < 614400 ? src[id] : 0.f);
            }
        }
        return;
    }
    bb -= 601;
    {
        // w1tq / w1tk: 4 gathered loads + packed store per thread
        const bool isQ = bb < 640;
        const float* w = isQ ? cq1 : ck1;
        bf16* wt = isQ ? w1tq : w1tk;
        const int lb = isQ ? bb : bb - 640;
        const int id4 = (lb * 256 + t) * 4;  // < 655360
        const int ho = id4 / 320, c0 = id4 % 320;
        bf16x4 ov;
#pragma unroll
        for (int j = 0; j < 4; ++j) {
            const int c = c0 + j;
            const float v =
                (c < 288) ? w[(long)ho * 288 + (c % 48) * 6 + (c / 48)] * 1e-3f : 0.f;
            ov[j] = (bf16)v;
        }
        *(bf16x4*)(wt + id4) = ov;
    }
}

// ---------------- conv1 + downstream-weight prep merged (3964 blocks) --------
// conv1 (blocks 0..1599) is latency-bound at ~6 blocks/CU; the prep-tail
// blocks (w2 transpose 2-rows/block, gbwF, giwF, gowT, gbaP) fill its idle
// issue slots instead of running as a serial prep phase. Union LDS = 24KB
// (conv1's own footprint), so conv1 residency is unchanged.
__global__ __launch_bounds__(256) void k_conv1p(
    const bf16* __restrict__ w1tk, const bf16* __restrict__ w1tq,
    const bf16* __restrict__ srcbf, bf16* __restrict__ r1k,
    bf16* __restrict__ r1q, const float* __restrict__ cq2,
    const float* __restrict__ ck2, const float* __restrict__ gbw,
    const float* __restrict__ giw, const float* __restrict__ gow,
    const float* __restrict__ gba, bf16* __restrict__ w2tq,
    bf16* __restrict__ w2tk, bf16* __restrict__ gbwF,
    bf16* __restrict__ giwF, bf16* __restrict__ gowT,
    bf16* __restrict__ gbaP) {
    __shared__ __align__(16) char smem[24576];
    const int t = threadIdx.x;
    int i = blockIdx.x;
    if (i >= 1600) {
        i -= 1600;
        float* lds = (float*)smem;
        if (i < 2048) {
            // w2 transpose: 2 rows/block (20KB LDS); packed bf16x4 stores
            const bool isQ = i < 1024;
            const int lb = isQ ? i : i - 1024;
            const float* wrow = (isQ ? cq2 : ck2) + (long)lb * 2 * 2560;
            bf16* orow = (isQ ? w2tq : w2tk) + (long)lb * 2 * 2560;
            float4* l4 = (float4*)lds;
            const float4* w4 = (const float4*)wrow;
#pragma unroll
            for (int j = 0; j < 5; ++j) l4[t + j * 256] = w4[t + j * 256];
            __syncthreads();
            for (int c = t * 4; c < 5120; c += 1024) {
                const int r = c / 2560, cc = c % 2560;
                const int k = cc >> 9, ii = cc & 511;
                bf16x4 ov;
#pragma unroll
                for (int j = 0; j < 4; ++j)
                    ov[j] = (bf16)lds[r * 2560 + (ii + j) * 5 + k];
                *(bf16x4*)(orow + c) = ov;
            }
            return;
        }
        i -= 2048;
        if (i < 256) {
            // gbwF: MFMA-fragment-order weights (round-2 layout)
            const int l = i >> 6, tile = i & 63;
            const int tr = tile >> 3, tc = tile & 7;
            const float* in = gbw + (long)l * 262144;
            bf16* o = gbwF + (long)l * 262144;
            // 64x64 tile via 16.6KB LDS [kl*65+ml] -> 2 halves of 32 k-rows
#pragma unroll
            for (int half = 0; half < 2; ++half) {
#pragma unroll
                for (int r = 0; r < 8; ++r) {
                    const int kl = (t >> 6) * 8 + r, ml = t & 63;
                    lds[kl * 65 + ml] =
                        in[(long)(tr * 64 + half * 32 + kl) * 512 + tc * 64 + ml];
                }
                __syncthreads();
                // this half covers sl = half (32 k) for both gl groups
                for (int j = t; j < 2048; j += 256) {
                    const int q = j >> 9, r4 = j & 511;
                    const int gl = q >> 1, jt = q & 1;
                    const int lane = r4 >> 3, e = r4 & 7;
                    const int fr = lane & 15, fq = lane >> 4;
                    const int kk = fq * 8 + e;  // 0..31 within half
                    const int ff = gl * 32 + jt * 16 + fr;
                    o[(long)(tc * 2 + gl) * 16384 +
                      (long)(tr * 2 + half) * 1024 + jt * 512 + r4] =
                        (bf16)lds[kk * 65 + ff];
                }
                __syncthreads();
            }
            return;
        }
        i -= 256;
        if (i < 32) {
            // giwF: fragment-order gc_in_w, 4/thread packed
            const int id4 = (i * 256 + t) * 4;  // < 32768
            const int g = id4 >> 11, r2 = id4 & 2047;
            const int s = r2 >> 10, r3 = r2 & 1023;
            const int jt = r3 >> 9, r4 = r3 & 511;
            const int lane = r4 >> 3, e0 = r4 & 7;
            const int fr = lane & 15, fq = lane >> 4;
            const int f = g * 32 + jt * 16 + fr;
            bf16x4 ov;
#pragma unroll
            for (int j = 0; j < 4; ++j) {
                const int k = s * 32 + fq * 8 + e0 + j;
                ov[j] = (bf16)(k < 20 ? giw[k * 512 + f] : 0.f);
            }
            *(bf16x4*)(giwF + id4) = ov;
            return;
        }
        i -= 32;
        if (i < 16) {
            // gowT [32][512], 4/thread packed
            const int id4 = (i * 256 + t) * 4;  // < 16384
            const int d = id4 >> 9, k0 = id4 & 511;
            bf16x4 ov;
#pragma unroll
            for (int j = 0; j < 4; ++j)
                ov[j] = (bf16)(d < 20 ? gow[(k0 + j) * 20 + d] : 0.f);
            *(bf16x4*)(gowT + id4) = ov;
            return;
        }
        i -= 16;
        {
            // gbaP [4][48][64], 4/thread packed
            const int id4 = (i * 256 + t) * 4;  // < 12288
            const int l = id4 / 3072, r = id4 % 3072;
            const int n = r >> 6, m0 = r & 63;
            bf16x4 ov;
#pragma unroll
            for (int j = 0; j < 4; ++j) {
                const int m = m0 + j;
                ov[j] = (bf16)(m < 48 ? gba[l * 2304 + n * 48 + m] : 0.f);
            }
            *(bf16x4*)(gbaP + id4) = ov;
        }
        return;
    }
    // ---- conv1 branch (blocks 0..1599), r13 code verbatim ----
    bf16* As = (bf16*)smem;
    bf16* Bs = (bf16*)(smem + 8192);
    int bx, by, bz;
    const bf16* A;
    bf16* C;
    int NT, toff;
    long cStr;
    if (i < 1280) {
        bz = i / 320;
        const int r = i % 320;
        bx = r % 40;
        by = r / 40;
        A = w1tk; C = r1k; NT = 20; toff = 0; cStr = 2621440L;
    } else {
        const int j = i - 1280;
        bz = j / 80;
        const int r = j % 80;
        bx = r % 10;
        by = r / 10;
        A = w1tq; C = r1q; NT = 5; toff = 40; cStr = 655360L;
    }
    const int wave = t >> 6;
    const int lane = t & 63;
    const int wm = (wave & 1) * 32;
    const int wn = (wave >> 1) * 64;
    const int m0 = by * 64;
    const int n0 = bx * 128;
    A += (long)bz * (512L * 320);

    const int srow = lane >> 3;
    const int gch = (lane & 7) ^ srow;
    const bf16* aptr[2];
    const bf16* bptr[4];
#pragma unroll
    for (int j = 0; j < 2; ++j) {
        const int ar = wave * 16 + j * 8 + srow;
        aptr[j] = A + (long)(m0 + ar) * 320 + gch * 8;
    }
#pragma unroll
    for (int j = 0; j < 4; ++j) {
        const int ar = wave * 32 + j * 8 + srow;
        const int n = n0 + ar;
        const long bbase = (long)(n / NT) * 2400 + (long)((n % NT) + toff) * 48;
        bptr[j] = srcbf + bbase + gch * 8;
    }

    floatx4 acc[4][2];
#pragma unroll
    for (int j = 0; j < 4; ++j)
#pragma unroll
        for (int q = 0; q < 2; ++q) acc[j][q] = (floatx4){0.f, 0.f, 0.f, 0.f};

    const int fr = lane & 15;
    const int fq = lane >> 4;
    const int fx = lane & 7;

    for (int k0 = 0; k0 < 320; k0 += 64) {
#pragma unroll
        for (int j = 0; j < 2; ++j)
            __builtin_amdgcn_global_load_lds(
                (const GLOBAL_AS void*)(aptr[j] + k0),
                (LDS_AS void*)(As + (wave * 16 + j * 8) * 64), 16, 0, 0);
#pragma unroll
        for (int j = 0; j < 4; ++j)
            __builtin_amdgcn_global_load_lds(
                (const GLOBAL_AS void*)(bptr[j] + k0),
                (LDS_AS void*)(Bs + (wave * 32 + j * 8) * 64), 16, 0, 0);
        __syncthreads();
#pragma unroll
        for (int kk = 0; kk < 2; ++kk) {
            bf16x8 af[2], bfr[4];
#pragma unroll
            for (int im = 0; im < 2; ++im)
                af[im] = *(const bf16x8*)(As + (wm + im * 16 + fr) * 64 +
                                          ((((kk << 2) + fq) ^ fx) << 3));
#pragma unroll
            for (int in = 0; in < 4; ++in)
                bfr[in] = *(const bf16x8*)(Bs + (wn + in * 16 + fr) * 64 +
                                           ((((kk << 2) + fq) ^ fx) << 3));
#pragma unroll
            for (int in = 0; in < 4; ++in)
#pragma unroll
                for (int im = 0; im < 2; ++im)
                    acc[in][im] = __builtin_amdgcn_mfma_f32_16x16x32_bf16(
                        af[im], bfr[in], acc[in][im], 0, 0, 0);
        }
        __syncthreads();
    }
#pragma unroll
    for (int in = 0; in < 4; ++in) {
        const long n = n0 + wn + in * 16 + fr;
#pragma unroll
        for (int im = 0; im < 2; ++im) {
            floatx4 v = acc[in][im];
            const long m = m0 + wm + im * 16 + (fq << 2);
            v.x = fmaxf(v.x, 0.f);
            v.y = fmaxf(v.y, 0.f);
            v.z = fmaxf(v.z, 0.f);
            v.w = fmaxf(v.w, 0.f);
            bf16* Cp = C + (long)bz * cStr + n * 512 + m;
            bf16x4 ov;
            ov[0] = (bf16)v.x;
            ov[1] = (bf16)v.y;
            ov[2] = (bf16)v.z;
            ov[3] = (bf16)v.w;
            *(bf16x4*)Cp = ov;
        }
    }
}

// ---------------- conv2 K+Q: window-dedup B staging (r9, frozen) -------------
__global__ __launch_bounds__(256) void k_conv2(
    const bf16* __restrict__ w2tk, const bf16* __restrict__ r1k,
    bf16* __restrict__ keyh, const bf16* __restrict__ w2tq,
    const bf16* __restrict__ r1q, bf16* __restrict__ qh) {
    const int K = 2560;
    int bx, by, bz;
    const bf16 *A, *B;
    bf16* C;
    bool kMode;
    long aStr, bStr, cStr;
    {
        const int i = blockIdx.x;
        if (i < 1024) {
            const int slot = i & 7;
            bz = slot >> 1;
            const int half = slot & 1;
            const int j = i >> 3;
            bx = half * 16 + (j & 15);
            by = j >> 4;
            A = w2tk; B = r1k; C = keyh; kMode = true;
            aStr = 512L * 2560; bStr = 2621440L; cStr = 2097152L;
        } else {
            const int j = i - 1024;
            bz = j >> 4;
            const int r = j & 15;
            bx = r & 1;
            by = r >> 1;
            A = w2tq; B = r1q; C = qh; kMode = false;
            aStr = 512L * 2560; bStr = 655360L; cStr = 131072L;
        }
    }
    __shared__ bf16 As[64 * 64];
    __shared__ bf16 Bs[160 * 64];
    const int tid = threadIdx.x;
    const int wave = tid >> 6;
    const int lane = tid & 63;
    const int wm = (wave & 1) * 32;
    const int wn = (wave >> 1) * 64;
    const int m0 = by * 64;
    const int n0 = bx * 128;
    A += (long)bz * aStr;
    B += (long)bz * bStr;

    const int srow = lane >> 3;
    const int gch = (lane & 7) ^ srow;
    const bf16* aptr[2];
#pragma unroll
    for (int i = 0; i < 2; ++i) {
        const int ar = wave * 16 + i * 8 + srow;
        aptr[i] = A + (long)(m0 + ar) * K + gch * 8;
    }

    floatx4 acc[4][2];
#pragma unroll
    for (int j = 0; j < 4; ++j)
#pragma unroll
        for (int i = 0; i < 2; ++i) acc[j][i] = (floatx4){0.f, 0.f, 0.f, 0.f};

    const int fr = lane & 15;
    const int fq = lane >> 4;
    const int fx = lane & 7;

    if (kMode) {
        const bf16* bptrK[5];
        int ldsBK[5];
#pragma unroll
        for (int j = 0; j < 5; ++j) {
            const int rloc = wave * 40 + j * 8 + srow;
            const int brel = rloc / 20, pos = rloc % 20;
            bptrK[j] = B + ((long)((bx * 8 + brel) * 20 + pos)) * 512 +
                       ((lane & 7) ^ (pos & 7)) * 8;
            ldsBK[j] = rloc * 64 + (lane & 7) * 8;
        }
        const int bq = wn >> 4;
        for (int c0i = 0; c0i < 8; ++c0i) {
            const int c0 = c0i * 64;
#pragma unroll
            for (int w = 0; w < 5; ++w) {
                const int k0 = w * 512 + c0;
#pragma unroll
                for (int i = 0; i < 2; ++i)
                    __builtin_amdgcn_global_load_lds(
                        (const GLOBAL_AS void*)(aptr[i] + k0),
                        (LDS_AS void*)(As + (wave * 16 + i * 8) * 64), 16, 0, 0);
                if (w == 0) {
#pragma unroll
                    for (int j = 0; j < 5; ++j)
                        __builtin_amdgcn_global_load_lds(
                            (const GLOBAL_AS void*)(bptrK[j] + c0),
                            (LDS_AS void*)(Bs + ldsBK[j]), 16, 0, 0);
                }
                __syncthreads();
#pragma unroll
                for (int kk = 0; kk < 2; ++kk) {
                    bf16x8 af[2], bfr[4];
#pragma unroll
                    for (int im = 0; im < 2; ++im)
                        af[im] = *(const bf16x8*)(As + (wm + im * 16 + fr) * 64 +
                                                  ((((kk << 2) + fq) ^ fx) << 3));
#pragma unroll
                    for (int nt = 0; nt < 4; ++nt) {
                        const int row = (bq + nt) * 20 + fr + w;
                        bfr[nt] = *(const bf16x8*)(
                            Bs + row * 64 +
                            ((((kk << 2) + fq) ^ ((fr + w) & 7)) << 3));
                    }
#pragma unroll
                    for (int nt = 0; nt < 4; ++nt)
#pragma unroll
                        for (int im = 0; im < 2; ++im)
                            acc[nt][im] = __builtin_amdgcn_mfma_f32_16x16x32_bf16(
                                af[im], bfr[nt], acc[nt][im], 0, 0, 0);
                }
                __syncthreads();
            }
        }
    } else {
        const bf16* bptr[4];
#pragma unroll
        for (int i = 0; i < 4; ++i) {
            const int ar = wave * 32 + i * 8 + srow;
            bptr[i] = B + (long)(n0 + ar) * K + gch * 8;
        }
        for (int k0 = 0; k0 < K; k0 += 64) {
#pragma unroll
            for (int i = 0; i < 2; ++i)
                __builtin_amdgcn_global_load_lds(
                    (const GLOBAL_AS void*)(aptr[i] + k0),
                    (LDS_AS void*)(As + (wave * 16 + i * 8) * 64), 16, 0, 0);
#pragma unroll
            for (int i = 0; i < 4; ++i)
                __builtin_amdgcn_global_load_lds(
                    (const GLOBAL_AS void*)(bptr[i] + k0),
                    (LDS_AS void*)(Bs + (wave * 32 + i * 8) * 64), 16, 0, 0);
            __syncthreads();
#pragma unroll
            for (int kk = 0; kk < 2; ++kk) {
                bf16x8 af[2], bfr[4];
#pragma unroll
                for (int im = 0; im < 2; ++im)
                    af[im] = *(const bf16x8*)(As + (wm + im * 16 + fr) * 64 +
                                              ((((kk << 2) + fq) ^ fx) << 3));
#pragma unroll
                for (int in = 0; in < 4; ++in)
                    bfr[in] = *(const bf16x8*)(Bs + (wn + in * 16 + fr) * 64 +
                                               ((((kk << 2) + fq) ^ fx) << 3));
#pragma unroll
                for (int in = 0; in < 4; ++in)
#pragma unroll
                    for (int im = 0; im < 2; ++im)
                        acc[in][im] = __builtin_amdgcn_mfma_f32_16x16x32_bf16(
                            af[im], bfr[in], acc[in][im], 0, 0, 0);
            }
            __syncthreads();
        }
    }
#pragma unroll
    for (int in = 0; in < 4; ++in) {
        const long n = n0 + wn + in * 16 + fr;
#pragma unroll
        for (int im = 0; im < 2; ++im) {
            floatx4 v = acc[in][im];
            const long m = m0 + wm + im * 16 + (fq << 2);
            v.x = fmaxf(v.x, 0.f);
            v.y = fmaxf(v.y, 0.f);
            v.z = fmaxf(v.z, 0.f);
            v.w = fmaxf(v.w, 0.f);
            bf16* Cp = C + (long)bz * cStr + n * 512 + m;
            bf16x4 ov;
            ov[0] = (bf16)v.x;
            ov[1] = (bf16)v.y;
            ov[2] = (bf16)v.z;
            ov[3] = (bf16)v.w;
            *(bf16x4*)Cp = ov;
        }
    }
}

// ---------------- fused attention block (one block per batch b, 512 thr) -----
// r14: lw/gia get their OWN LDS buffers (106KB total, still 1 block/CU at
// grid=256) staged right after the score phase -> the loads retire under the
// sv/L compute instead of a fully-exposed serial phase between barriers.
__global__ __launch_bounds__(512) void k_att(
    const bf16* __restrict__ qh, const bf16* __restrict__ keyh,
    const float* __restrict__ src, const float* __restrict__ dct10,
    const float* __restrict__ lw, const float* __restrict__ lb,
    const float* __restrict__ gia, float* __restrict__ dctin,
    bf16* __restrict__ z0) {
    const int b = blockIdx.x;
    const int t = threadIdx.x;
    __shared__ float BIG[9216];
    __shared__ float lwS[9216];
    __shared__ float giaS[2304];
    __shared__ float WD[2400];
    __shared__ float D[350];
    __shared__ float L[1920];
    __shared__ float dinS[960];
    __shared__ float sS[64];
    __shared__ float awS[64];

    {
        const int g = t >> 3, lane = t & 7;
        const int h = g >> 4, tt = g & 15;
        const bf16* q = qh + ((long)h * 256 + b) * 512 + lane * 64;
        const bf16* kr = keyh + (long)h * 2097152 + ((long)b * 16 + tt) * 512 + lane * 64;
        float p = 0.f;
#pragma unroll
        for (int i = 0; i < 8; ++i) {
            const bf16x8 qv = *(const bf16x8*)(q + i * 8);
            const bf16x8 kv = *(const bf16x8*)(kr + i * 8);
#pragma unroll
            for (int j = 0; j < 8; ++j) p = fmaf((float)qv[j], (float)kv[j], p);
        }
        p += __shfl_down(p, 4, 8);
        p += __shfl_down(p, 2, 8);
        p += __shfl_down(p, 1, 8);
        if (lane == 0) sS[g] = p + 1e-15f;
    }
    for (int i = t; i < 2400; i += 512) WD[i] = src[(long)b * 2400 + i];
    for (int i = t; i < 350; i += 512) D[i] = dct10[i];
    // early staging: loads issue now, retire under sv/L phases
    for (int i = t; i < 9216; i += 512) lwS[i] = lw[i];
    for (int i = t; i < 2304; i += 512) giaS[i] = gia[i];
    __syncthreads();
    if (t < 4) {
        float s = 0.f;
#pragma unroll
        for (int k = 0; k < 16; ++k) s += sS[t * 16 + k];
        const float inv = 1.f / s;
#pragma unroll
        for (int k = 0; k < 16; ++k) awS[t * 16 + k] = sS[t * 16 + k] * inv;
    }
    __syncthreads();
    // sv windows: thread t<480 owns (f=t/10, d=t%10); D row in registers
    if (t < 480) {
        const int f = t / 10, d = t % 10;
        float dreg[35];
#pragma unroll
        for (int v = 0; v < 35; ++v) dreg[v] = D[d * 35 + v];
#pragma unroll 2
        for (int n = 0; n < 16; ++n) {
            float acc = 0.f;
#pragma unroll
            for (int v = 0; v < 35; ++v)
                acc = fmaf(dreg[v], WD[(n + v) * 48 + f], acc);
            BIG[n * 480 + t] = acc;
        }
        // dctin cols 0..9 (gather rows 40..49, last row repeated)
        float acc = 0.f;
#pragma unroll
        for (int v = 0; v < 10; ++v)
            acc = fmaf(dreg[v], WD[(40 + v) * 48 + f], acc);
        float cs = 0.f;
#pragma unroll
        for (int v = 10; v < 35; ++v) cs += dreg[v];
        acc = fmaf(cs, WD[49 * 48 + f], acc);
        dinS[f * 20 + d] = acc;
        dctin[(long)b * 960 + f * 20 + d] = acc;
    }
    __syncthreads();
    for (int p = 0; p < 4; ++p) {
        const int idx = t + p * 512;
        if (idx < 1920) {
            const int h = idx / 480, j = idx % 480;
            float acc = 0.f;
#pragma unroll
            for (int k = 0; k < 16; ++k)
                acc = fmaf(awS[h * 16 + k], BIG[k * 480 + j], acc);
            L[idx] = acc;
        }
    }
    __syncthreads();
    if (t < 480) {
        const int n = t / 10, d = t % 10;
        float acc = lb[n];
#pragma unroll
        for (int h = 0; h < 4; ++h)
#pragma unroll
            for (int f = 0; f < 48; ++f)
                acc = fmaf(lwS[n * 192 + h * 48 + f], L[h * 480 + f * 10 + d], acc);
        dinS[n * 20 + 10 + d] = acc;
        dctin[(long)b * 960 + n * 20 + 10 + d] = acc;
    }
    __syncthreads();
    for (int p = 0; p < 2; ++p) {
        const int idx = t + p * 512;
        if (idx < 960) {
            const int n = idx / 20, d = idx % 20;
            float acc = 0.f;
#pragma unroll
            for (int m = 0; m < 48; ++m)
                acc = fmaf(giaS[n * 48 + m], dinS[m * 20 + d], acc);
            z0[((long)b * 48 + n) * 64 + d] = (bf16)acc;
        }
    }
    for (int i = t; i < 2112; i += 512) {
        const int n = i / 44, c = 20 + i % 44;
        z0[((long)b * 48 + n) * 64 + c] = (bf16)0.f;
    }
}

// ---------------- GCN mega-kernel (fragment-W + packed epilogue) -------------
template <bool TOUT, int S>
__device__ __forceinline__ void gcn_matmul3(
    const bf16* __restrict__ zSrc, const bf16* __restrict__ Wf,
    const float* __restrict__ bias, const bf16* __restrict__ resT,
    bf16* __restrict__ outS, const int wave, const int lane) {
    const int fr = lane & 15, fq = lane >> 4;
    const int f0 = wave * 32;
    floatx4 acc[3][2];
#pragma unroll
    for (int it = 0; it < 3; ++it)
#pragma unroll
        for (int jt = 0; jt < 2; ++jt) acc[it][jt] = (floatx4){0.f, 0.f, 0.f, 0.f};
    const bf16* wp = Wf + (long)wave * (S * 1024) + (lane << 3);
    bf16x8 w0[4], w1[4];
    constexpr int PRE = (S < 3) ? S : 3;
#pragma unroll
    for (int s = 0; s < PRE; ++s) {
        w0[s] = *(const bf16x8*)(wp + s * 1024);
        w1[s] = *(const bf16x8*)(wp + s * 1024 + 512);
    }
#pragma unroll
    for (int s = 0; s < S; ++s) {
        bf16x8 af[3];
#pragma unroll
        for (int it = 0; it < 3; ++it)
            af[it] = *(const bf16x8*)(zSrc + (it * 16 + fr) * 520 + s * 32 + fq * 8);
        if (s + 3 < S) {
            const int ns = (s + 3) & 3;
            w0[ns] = *(const bf16x8*)(wp + (s + 3) * 1024);
            w1[ns] = *(const bf16x8*)(wp + (s + 3) * 1024 + 512);
        }
        const int sl = s & 3;
#pragma unroll
        for (int it = 0; it < 3; ++it) {
            acc[it][0] = __builtin_amdgcn_mfma_f32_16x16x32_bf16(af[it], w0[sl],
                                                                acc[it][0], 0, 0, 0);
            acc[it][1] = __builtin_amdgcn_mfma_f32_16x16x32_bf16(af[it], w1[sl],
                                                                acc[it][1], 0, 0, 0);
        }
    }
#pragma unroll
    for (int jt = 0; jt < 2; ++jt) {
        const int f = f0 + jt * 16 + fr;
        const float bv = bias[f];
#pragma unroll
        for (int it = 0; it < 3; ++it) {
            const int ir0 = it * 16 + fq * 4;
            float v[4];
#pragma unroll
            for (int r = 0; r < 4; ++r)
                v[r] = tanh_fast((acc[it][jt][r] + bv) * BN_SCALE_F);
            if (resT) {
                const bf16x4 rv = *(const bf16x4*)(resT + f * 48 + ir0);
#pragma unroll
                for (int r = 0; r < 4; ++r) v[r] += (float)rv[r];
            }
            if (TOUT) {
                bf16x4 ov;
#pragma unroll
                for (int r = 0; r < 4; ++r) ov[r] = (bf16)v[r];
                *(bf16x4*)(outS + f * 48 + ir0) = ov;
            } else {
#pragma unroll
                for (int r = 0; r < 4; ++r)
                    outS[(ir0 + r) * 520 + f] = (bf16)v[r];
            }
        }
    }
}

__device__ __forceinline__ void gcn_attmul2(const bf16* __restrict__ gA,
                                            const bf16* __restrict__ YinT,
                                            bf16* __restrict__ zOut,
                                            const int wave, const int lane) {
    const int fr = lane & 15, fq = lane >> 4;
    const int f0 = wave * 32;
    floatx4 acc[3][2];
#pragma unroll
    for (int it = 0; it < 3; ++it)
#pragma unroll
        for (int jt = 0; jt < 2; ++jt) acc[it][jt] = (floatx4){0.f, 0.f, 0.f, 0.f};
    bf16x8 af0[3], af1[3], bv0[2], bv1[2];
#pragma unroll
    for (int it = 0; it < 3; ++it) {
        af0[it] = *(const bf16x8*)(gA + (it * 16 + fr) * 64 + fq * 8);
        af1[it] = *(const bf16x8*)(gA + (it * 16 + fr) * 64 + 32 + fq * 8);
    }
#pragma unroll
    for (int jt = 0; jt < 2; ++jt) {
        const int f = f0 + jt * 16 + fr;
        bv0[jt] = *(const bf16x8*)(YinT + f * 48 + fq * 8);
        bv1[jt] = *(const bf16x8*)(YinT + f * 48 + 32 + fq * 8);
    }
#pragma unroll
    for (int it = 0; it < 3; ++it)
#pragma unroll
        for (int jt = 0; jt < 2; ++jt) {
            acc[it][jt] = __builtin_amdgcn_mfma_f32_16x16x32_bf16(af0[it], bv0[jt],
                                                                 acc[it][jt], 0, 0, 0);
            acc[it][jt] = __builtin_amdgcn_mfma_f32_16x16x32_bf16(af1[it], bv1[jt],
                                                                 acc[it][jt], 0, 0, 0);
        }
#pragma unroll
    for (int jt = 0; jt < 2; ++jt) {
        const int f = f0 + jt * 16 + fr;
#pragma unroll
        for (int it = 0; it < 3; ++it)
#pragma unroll
            for (int r = 0; r < 4; ++r)
                zOut[(it * 16 + fq * 4 + r) * 520 + f] = (bf16)acc[it][jt][r];
    }
}

__global__ __launch_bounds__(1024) void k_gcn(
    const bf16* __restrict__ z0, const bf16* __restrict__ giwF,
    const float* __restrict__ gib, const bf16* __restrict__ gbwF,
    const bf16* __restrict__ gbaP, const float* __restrict__ gbb,
    const float* __restrict__ goa, const bf16* __restrict__ gowT,
    const float* __restrict__ gob, const float* __restrict__ dctin,
    const float* __restrict__ dct10, float* __restrict__ out) {
    const int b = blockIdx.x;
    const int t = threadIdx.x;
    const int wave = t >> 6, lane = t & 63;
    // yaS: transposed Y^T[512][48] (+16 zero tail) OR final normal [48][520]
    __shared__ __align__(16) bf16 yaS[24976];
    __shared__ __align__(16) bf16 ybS[24592];
    __shared__ __align__(16) bf16 zS[48 * 520];

    if (t < 384) {
        const int r = t >> 3, c = t & 7;
        *(bf16x8*)(zS + r * 520 + c * 8) =
            *(const bf16x8*)(z0 + ((long)b * 48 + r) * 64 + c * 8);
    } else if (t < 400) {
        yaS[24576 + (t - 384)] = (bf16)0.f;
    } else if (t < 416) {
        ybS[24576 + (t - 400)] = (bf16)0.f;
    }
    __syncthreads();
    gcn_matmul3<true, 2>(zS, giwF, gib, nullptr, yaS, wave, lane);
    __syncthreads();

#pragma unroll
    for (int l = 0; l < 4; ++l) {
        const bf16* YinT = (l == 0 || l == 3) ? yaS : ybS;
        gcn_attmul2(gbaP + l * 3072, YinT, zS, wave, lane);
        __syncthreads();
        const bf16* Res = (l == 1) ? yaS : (l == 3 ? ybS : nullptr);
        if (l < 3)
            gcn_matmul3<true, 16>(zS, gbwF + (long)l * 262144, gbb + l * 512,
                                  Res, (l < 2) ? ybS : yaS, wave, lane);
        else
            gcn_matmul3<false, 16>(zS, gbwF + 3L * 262144, gbb + 3 * 512, Res,
                                   yaS, wave, lane);
        __syncthreads();
    }
    // ---- gc_out + iDCT (final Y = yaS, normal [48][520] layout) ----
    float* T2 = (float*)ybS;             // 960 f32
    float* dS = ((float*)ybS) + 960;     // 960 f32
    float* goaS = ((float*)ybS) + 1920;  // 2304 f32
    float* Df = ((float*)ybS) + 4224;    // 350 f32
    if (t < 384) {
        // 6 waves: T2[48][20] = Yfin(48x512) x gow(512x20) via MFMA
        const int fr2 = lane & 15, fq2 = lane >> 4;
        const int it = wave >> 1, jt = wave & 1;
        floatx4 accT = (floatx4){0.f, 0.f, 0.f, 0.f};
        const bf16* ap = yaS + (it * 16 + fr2) * 520 + fq2 * 8;
        const bf16* gp = gowT + (long)(jt * 16 + fr2) * 512 + fq2 * 8;
        for (int k0 = 0; k0 < 512; k0 += 32) {
            const bf16x8 av = *(const bf16x8*)(ap + k0);
            const bf16x8 gv = *(const bf16x8*)(gp + k0);
            accT = __builtin_amdgcn_mfma_f32_16x16x32_bf16(av, gv, accT, 0, 0, 0);
        }
        const int d = jt * 16 + fr2;
        if (d < 20) {
#pragma unroll
            for (int r = 0; r < 4; ++r) {
                const int m = it * 16 + fq2 * 4 + r;
                T2[m * 20 + d] = accT[r];
            }
        }
    } else {
        for (int i = t - 384; i < 2304; i += 640) goaS[i] = goa[i];
        for (int i = t - 384; i < 350; i += 640) Df[i] = dct10[i];
    }
    __syncthreads();
    if (t < 960) {
        const int n = t / 20, d = t % 20;
        float acc = gob[d] + dctin[(long)b * 960 + t];
#pragma unroll
        for (int m = 0; m < 48; ++m)
            acc = fmaf(goaS[n * 48 + m], T2[m * 20 + d], acc);
        dS[t] = acc;
    }
    __syncthreads();
    for (int e = t; e < 1680; e += 1024) {
        const int v = e / 48, n = e % 48;
        float acc = 0.f;
#pragma unroll
        for (int d = 0; d < 10; ++d)
            acc = fmaf(Df[d * 35 + v], dS[n * 20 + d], acc);
        out[(long)b * 1680 + e] = acc;
    }
}

// ---------------------------------------------------------------------------
// Workspace (BYTE offsets). keyh bf16 (16.8 MB) aliases WS_T; z0 at WS_T+17MB.
// gowT/gbaP live in the (otherwise unused) WS_PAD0 region.
// ---------------------------------------------------------------------------
static constexpr size_t WS_DCT10 = 0;
static constexpr size_t WS_ATTW = 1536;
static constexpr size_t WS_QH = WS_ATTW + 65536;
static constexpr size_t WS_DCTIN = WS_QH + 2097152;
static constexpr size_t WS_DCTOUT = WS_DCTIN + 983040;
static constexpr size_t WS_SRCVAL = WS_DCTOUT + 983040;
static constexpr size_t WS_PAD0 = WS_SRCVAL + 7864320;
static constexpr size_t WS_GOWT = WS_PAD0;                  // 32*512*2 = 32768
static constexpr size_t WS_GBAP = WS_PAD0 + 32768;          // 4*48*64*2 = 24576
static constexpr size_t WS_SRCBF = WS_PAD0 + 8388608;
static constexpr size_t WS_W1TQ = WS_SRCBF + 1229824;
static constexpr size_t WS_W1TK = WS_W1TQ + 1310720;
static constexpr size_t WS_W2TQ = WS_W1TK + 1310720;
static constexpr size_t WS_W2TK = WS_W2TQ + 10485760;
static constexpr size_t WS_GBWT = WS_W2TK + 10485760;
static constexpr size_t WS_R1K = WS_GBWT + 2097152;
static constexpr size_t WS_R1Q = WS_R1K + 20971520;
static constexpr size_t WS_T = WS_R1Q + 5242880;
static constexpr size_t WS_GIWP = WS_T + 50331648;
static constexpr size_t WS_KEYH = WS_T;
static constexpr size_t WS_Z0 = WS_T + 17825792;

extern "C" void kernel_launch(void* const* d_in, const int* in_sizes, int n_in,
                              void* d_out, int out_size, void* d_ws,
                              size_t ws_size, hipStream_t stream) {
    const float* src = (const float*)d_in[0];
    const float* cq1 = (const float*)d_in[1];
    const float* cq2 = (const float*)d_in[2];
    const float* ck1 = (const float*)d_in[3];
    const float* ck2 = (const float*)d_in[4];
    const float* lw = (const float*)d_in[5];
    const float* lb = (const float*)d_in[6];
    const float* giw = (const float*)d_in[7];
    const float* gia = (const float*)d_in[8];
    const float* gib = (const float*)d_in[9];
    const float* gbw = (const float*)d_in[10];
    const float* gba = (const float*)d_in[11];
    const float* gbb = (const float*)d_in[12];
    const float* gow = (const float*)d_in[13];
    const float* goa = (const float*)d_in[14];
    const float* gob = (const float*)d_in[15];
    float* out = (float*)d_out;
    char* ws = (char*)d_ws;

    float* dct10 = (float*)(ws + WS_DCT10);
    bf16* qh = (bf16*)(ws + WS_QH);
    float* dctin = (float*)(ws + WS_DCTIN);
    bf16* keyh = (bf16*)(ws + WS_KEYH);
    bf16* srcbf = (bf16*)(ws + WS_SRCBF);
    bf16* w1tq = (bf16*)(ws + WS_W1TQ);
    bf16* w1tk = (bf16*)(ws + WS_W1TK);
    bf16* w2tq = (bf16*)(ws + WS_W2TQ);
    bf16* w2tk = (bf16*)(ws + WS_W2TK);
    bf16* gbwF = (bf16*)(ws + WS_GBWT);
    bf16* r1k = (bf16*)(ws + WS_R1K);
    bf16* r1q = (bf16*)(ws + WS_R1Q);
    bf16* giwF = (bf16*)(ws + WS_GIWP);
    bf16* gowT = (bf16*)(ws + WS_GOWT);
    bf16* gbaP = (bf16*)(ws + WS_GBAP);
    bf16* z0 = (bf16*)(ws + WS_Z0);

    // 1. slim prep: only conv1 inputs (dct10, srcbf, w1t) -- 1883 blocks
    k_prep<<<1883, 256, 0, stream>>>(src, cq1, ck1, dct10, srcbf, w1tq, w1tk);

    // 2. conv1 + downstream-weight prep merged (3964 blocks): prep-tail
    //    blocks fill conv1's idle latency slots
    k_conv1p<<<3964, 256, 0, stream>>>(w1tk, w1tq, srcbf, r1k, r1q, cq2, ck2,
                                       gbw, giw, gow, gba, w2tq, w2tk, gbwF,
                                       giwF, gowT, gbaP);

    // 3. conv2 K+Q: window-dedup B staging, 1088 blocks (frozen at r9)
    k_conv2<<<1088, 256, 0, stream>>>(w2tk, r1k, keyh, w2tq, r1q, qh);

    // 4. fused attention block -> dctin (fp32), z0 (bf16); early lw/gia stage
    k_att<<<256, 512, 0, stream>>>(qh, keyh, src, dct10, lw, lb, gia, dctin, z0);

    // 5. whole GCN in one dispatch (fragment-W + packed epilogue)
    k_gcn<<<256, 1024, 0, stream>>>(z0, giwF, gib, gbwF, gbaP, gbb, goa, gowT,
                                    gob, dctin, dct10, out);
}

// Round 15
// 291.494 us; speedup vs baseline: 1.0474x; 1.0474x over previous
//
#include <hip/hip_runtime.h>
#include <math.h>

// ---------------------------------------------------------------------------
// Problem constants (bs=256, in_feat=48, d_model=512, dct_n=10, input_n=50,
// output_n=25, KERNEL=10, HEADS=4, vl=35, vn=16)
// ---------------------------------------------------------------------------
static constexpr float BN_SCALE_F = 0.9999950000374997f;

typedef __bf16 bf16;
typedef bf16 bf16x8 __attribute__((ext_vector_type(8)));
typedef bf16 bf16x4 __attribute__((ext_vector_type(4)));
typedef float floatx4 __attribute__((ext_vector_type(4)));

#define GLOBAL_AS __attribute__((address_space(1)))
#define LDS_AS __attribute__((address_space(3)))

__device__ __forceinline__ float tanh_fast(float x) {
    const float e = __expf(2.f * x);
    return 1.f - 2.f / (e + 1.f);
}

// ---------------- mega prep (vectorized, 3223 blocks) ------------------------
__global__ __launch_bounds__(256) void k_prep(
    const float* __restrict__ src, const float* __restrict__ cq1,
    const float* __restrict__ ck1, const float* __restrict__ cq2,
    const float* __restrict__ ck2, const float* __restrict__ gbw,
    const float* __restrict__ giw, const float* __restrict__ gow,
    const float* __restrict__ gba, float* __restrict__ dct10,
    bf16* __restrict__ srcbf, bf16* __restrict__ w1tq, bf16* __restrict__ w1tk,
    bf16* __restrict__ w2tq, bf16* __restrict__ w2tk, bf16* __restrict__ gbwF,
    bf16* __restrict__ giwF, bf16* __restrict__ gowT, bf16* __restrict__ gbaP) {
    __shared__ __align__(16) float lds[10240];
    int bb = blockIdx.x;
    const int t = threadIdx.x;
    if (bb < 2) {
        int id = bb * 256 + t;
        if (id < 350) {
            int k = id / 35, i = id % 35;
            double w = (k == 0) ? sqrt(1.0 / 35.0) : sqrt(2.0 / 35.0);
            dct10[id] = (float)(w * cos(3.14159265358979323846 * (i + 0.5) * k / 35.0));
        }
        return;
    }
    bb -= 2;
    if (bb < 601) {
        // srcbf: float4 -> bf16x4, 4 elems/thread (tail zero-padded)
        const int id4 = (bb * 256 + t) * 4;
        if (id4 + 3 < 614400) {
            const float4 v = *(const float4*)(src + id4);
            bf16x4 ov;
            ov[0] = (bf16)v.x; ov[1] = (bf16)v.y;
            ov[2] = (bf16)v.z; ov[3] = (bf16)v.w;
            *(bf16x4*)(srcbf + id4) = ov;
        } else if (id4 < 614656) {
#pragma unroll
            for (int j = 0; j < 4; ++j) {
                const int id = id4 + j;
                if (id < 614656) srcbf[id] = (bf16)(id < 614400 ? src[id] : 0.f);
            }
        }
        return;
    }
    bb -= 601;
    if (bb < 1280) {
        // w1tq / w1tk: 4 gathered loads + packed store per thread
        const bool isQ = bb < 640;
        const float* w = isQ ? cq1 : ck1;
        bf16* wt = isQ ? w1tq : w1tk;
        const int lb = isQ ? bb : bb - 640;
        const int id4 = (lb * 256 + t) * 4;  // < 655360
        const int ho = id4 / 320, c0 = id4 % 320;
        bf16x4 ov;
#pragma unroll
        for (int j = 0; j < 4; ++j) {
            const int c = c0 + j;
            const float v =
                (c < 288) ? w[(long)ho * 288 + (c % 48) * 6 + (c / 48)] * 1e-3f : 0.f;
            ov[j] = (bf16)v;
        }
        *(bf16x4*)(wt + id4) = ov;
        return;
    }
    bb -= 1280;
    if (bb < 1024) {
        // w2 transpose: 4 rows/block; float4 staging, packed bf16x4 stores
        const bool isQ = bb < 512;
        const int rb = isQ ? bb : bb - 512;
        const float* wrow = (isQ ? cq2 : ck2) + (long)rb * 4 * 2560;
        bf16* orow = (isQ ? w2tq : w2tk) + (long)rb * 4 * 2560;
        float4* l4 = (float4*)lds;
        const float4* w4 = (const float4*)wrow;
#pragma unroll
        for (int i = 0; i < 10; ++i) l4[t + i * 256] = w4[t + i * 256];
        __syncthreads();
        for (int c = t * 4; c < 10240; c += 1024) {
            const int r = c / 2560, cc = c % 2560;
            const int k = cc >> 9, ii = cc & 511;
            bf16x4 ov;
#pragma unroll
            for (int j = 0; j < 4; ++j)
                ov[j] = (bf16)lds[r * 2560 + (ii + j) * 5 + k];
            *(bf16x4*)(orow + c) = ov;
        }
        return;
    }
    bb -= 1024;
    if (bb < 256) {
        // gbwF: MFMA-fragment-order weights (round-2 layout, unchanged)
        const int l = bb >> 6, tile = bb & 63;
        const int tr = tile >> 3, tc = tile & 7;
        const float* in = gbw + (long)l * 262144;
        bf16* o = gbwF + (long)l * 262144;
#pragma unroll
        for (int r = 0; r < 16; ++r) {
            const int kl = (t >> 6) * 16 + r, ml = t & 63;
            lds[kl * 65 + ml] = in[(long)(tr * 64 + kl) * 512 + tc * 64 + ml];
        }
        __syncthreads();
        for (int j = t; j < 4096; j += 256) {
            const int q = j >> 9, r4 = j & 511;
            const int gl = q >> 2, sl = (q >> 1) & 1, jt = q & 1;
            const int lane = r4 >> 3, e = r4 & 7;
            const int fr = lane & 15, fq = lane >> 4;
            const int kk = sl * 32 + fq * 8 + e;
            const int ff = gl * 32 + jt * 16 + fr;
            o[(long)(tc * 2 + gl) * 16384 + (long)(tr * 2 + sl) * 1024 + jt * 512 + r4] =
                (bf16)lds[kk * 65 + ff];
        }
        return;
    }
    bb -= 256;
    if (bb < 32) {
        // giwF: fragment-order gc_in_w, 4/thread packed
        const int id4 = (bb * 256 + t) * 4;  // < 32768
        const int g = id4 >> 11, r2 = id4 & 2047;
        const int s = r2 >> 10, r3 = r2 & 1023;
        const int jt = r3 >> 9, r4 = r3 & 511;
        const int lane = r4 >> 3, e0 = r4 & 7;
        const int fr = lane & 15, fq = lane >> 4;
        const int f = g * 32 + jt * 16 + fr;
        bf16x4 ov;
#pragma unroll
        for (int j = 0; j < 4; ++j) {
            const int k = s * 32 + fq * 8 + e0 + j;
            ov[j] = (bf16)(k < 20 ? giw[k * 512 + f] : 0.f);
        }
        *(bf16x4*)(giwF + id4) = ov;
        return;
    }
    bb -= 32;
    if (bb < 16) {
        // gowT [32][512], 4/thread packed
        const int id4 = (bb * 256 + t) * 4;  // < 16384
        const int d = id4 >> 9, k0 = id4 & 511;
        bf16x4 ov;
#pragma unroll
        for (int j = 0; j < 4; ++j)
            ov[j] = (bf16)(d < 20 ? gow[(k0 + j) * 20 + d] : 0.f);
        *(bf16x4*)(gowT + id4) = ov;
        return;
    }
    bb -= 16;
    {
        // gbaP [4][48][64], 4/thread packed
        const int id4 = (bb * 256 + t) * 4;  // < 12288
        const int l = id4 / 3072, r = id4 % 3072;
        const int n = r >> 6, m0 = r & 63;
        bf16x4 ov;
#pragma unroll
        for (int j = 0; j < 4; ++j) {
            const int m = m0 + j;
            ov[j] = (bf16)(m < 48 ? gba[l * 2304 + n * 48 + m] : 0.f);
        }
        *(bf16x4*)(gbaP + id4) = ov;
    }
}

// ---------------- conv1 K+Q fused: 64x128 tiles, 1600 blocks -----------------
__global__ __launch_bounds__(256) void k_conv1(
    const bf16* __restrict__ w1tk, const bf16* __restrict__ w1tq,
    const bf16* __restrict__ srcbf, bf16* __restrict__ r1k,
    bf16* __restrict__ r1q) {
    int bx, by, bz;
    const bf16* A;
    bf16* C;
    int NT, toff;
    long cStr;
    {
        const int i = blockIdx.x;
        if (i < 1280) {
            bz = i / 320;
            const int r = i % 320;
            bx = r % 40;
            by = r / 40;
            A = w1tk; C = r1k; NT = 20; toff = 0; cStr = 2621440L;
        } else {
            const int j = i - 1280;
            bz = j / 80;
            const int r = j % 80;
            bx = r % 10;
            by = r / 10;
            A = w1tq; C = r1q; NT = 5; toff = 40; cStr = 655360L;
        }
    }
    __shared__ bf16 As[64 * 64];
    __shared__ bf16 Bs[128 * 64];
    const int tid = threadIdx.x;
    const int wave = tid >> 6;
    const int lane = tid & 63;
    const int wm = (wave & 1) * 32;
    const int wn = (wave >> 1) * 64;
    const int m0 = by * 64;
    const int n0 = bx * 128;
    A += (long)bz * (512L * 320);

    const int srow = lane >> 3;
    const int gch = (lane & 7) ^ srow;
    const bf16* aptr[2];
    const bf16* bptr[4];
#pragma unroll
    for (int i = 0; i < 2; ++i) {
        const int ar = wave * 16 + i * 8 + srow;
        aptr[i] = A + (long)(m0 + ar) * 320 + gch * 8;
    }
#pragma unroll
    for (int i = 0; i < 4; ++i) {
        const int ar = wave * 32 + i * 8 + srow;
        const int n = n0 + ar;
        const long bbase = (long)(n / NT) * 2400 + (long)((n % NT) + toff) * 48;
        bptr[i] = srcbf + bbase + gch * 8;
    }

    floatx4 acc[4][2];
#pragma unroll
    for (int j = 0; j < 4; ++j)
#pragma unroll
        for (int i = 0; i < 2; ++i) acc[j][i] = (floatx4){0.f, 0.f, 0.f, 0.f};

    const int fr = lane & 15;
    const int fq = lane >> 4;
    const int fx = lane & 7;

    for (int k0 = 0; k0 < 320; k0 += 64) {
#pragma unroll
        for (int i = 0; i < 2; ++i)
            __builtin_amdgcn_global_load_lds(
                (const GLOBAL_AS void*)(aptr[i] + k0),
                (LDS_AS void*)(As + (wave * 16 + i * 8) * 64), 16, 0, 0);
#pragma unroll
        for (int i = 0; i < 4; ++i)
            __builtin_amdgcn_global_load_lds(
                (const GLOBAL_AS void*)(bptr[i] + k0),
                (LDS_AS void*)(Bs + (wave * 32 + i * 8) * 64), 16, 0, 0);
        __syncthreads();
#pragma unroll
        for (int kk = 0; kk < 2; ++kk) {
            bf16x8 af[2], bfr[4];
#pragma unroll
            for (int im = 0; im < 2; ++im)
                af[im] = *(const bf16x8*)(As + (wm + im * 16 + fr) * 64 +
                                          ((((kk << 2) + fq) ^ fx) << 3));
#pragma unroll
            for (int in = 0; in < 4; ++in)
                bfr[in] = *(const bf16x8*)(Bs + (wn + in * 16 + fr) * 64 +
                                           ((((kk << 2) + fq) ^ fx) << 3));
#pragma unroll
            for (int in = 0; in < 4; ++in)
#pragma unroll
                for (int im = 0; im < 2; ++im)
                    acc[in][im] = __builtin_amdgcn_mfma_f32_16x16x32_bf16(
                        af[im], bfr[in], acc[in][im], 0, 0, 0);
        }
        __syncthreads();
    }
#pragma unroll
    for (int in = 0; in < 4; ++in) {
        const long n = n0 + wn + in * 16 + fr;
#pragma unroll
        for (int im = 0; im < 2; ++im) {
            floatx4 v = acc[in][im];
            const long m = m0 + wm + im * 16 + (fq << 2);
            v.x = fmaxf(v.x, 0.f);
            v.y = fmaxf(v.y, 0.f);
            v.z = fmaxf(v.z, 0.f);
            v.w = fmaxf(v.w, 0.f);
            bf16* Cp = C + (long)bz * cStr + n * 512 + m;
            bf16x4 ov;
            ov[0] = (bf16)v.x;
            ov[1] = (bf16)v.y;
            ov[2] = (bf16)v.z;
            ov[3] = (bf16)v.w;
            *(bf16x4*)Cp = ov;
        }
    }
}

// ---------------- conv2 K+Q: window-dedup B staging (r9, frozen) -------------
__global__ __launch_bounds__(256) void k_conv2(
    const bf16* __restrict__ w2tk, const bf16* __restrict__ r1k,
    bf16* __restrict__ keyh, const bf16* __restrict__ w2tq,
    const bf16* __restrict__ r1q, bf16* __restrict__ qh) {
    const int K = 2560;
    int bx, by, bz;
    const bf16 *A, *B;
    bf16* C;
    bool kMode;
    long aStr, bStr, cStr;
    {
        const int i = blockIdx.x;
        if (i < 1024) {
            const int slot = i & 7;
            bz = slot >> 1;
            const int half = slot & 1;
            const int j = i >> 3;
            bx = half * 16 + (j & 15);
            by = j >> 4;
            A = w2tk; B = r1k; C = keyh; kMode = true;
            aStr = 512L * 2560; bStr = 2621440L; cStr = 2097152L;
        } else {
            const int j = i - 1024;
            bz = j >> 4;
            const int r = j & 15;
            bx = r & 1;
            by = r >> 1;
            A = w2tq; B = r1q; C = qh; kMode = false;
            aStr = 512L * 2560; bStr = 655360L; cStr = 131072L;
        }
    }
    __shared__ bf16 As[64 * 64];
    __shared__ bf16 Bs[160 * 64];
    const int tid = threadIdx.x;
    const int wave = tid >> 6;
    const int lane = tid & 63;
    const int wm = (wave & 1) * 32;
    const int wn = (wave >> 1) * 64;
    const int m0 = by * 64;
    const int n0 = bx * 128;
    A += (long)bz * aStr;
    B += (long)bz * bStr;

    const int srow = lane >> 3;
    const int gch = (lane & 7) ^ srow;
    const bf16* aptr[2];
#pragma unroll
    for (int i = 0; i < 2; ++i) {
        const int ar = wave * 16 + i * 8 + srow;
        aptr[i] = A + (long)(m0 + ar) * K + gch * 8;
    }

    floatx4 acc[4][2];
#pragma unroll
    for (int j = 0; j < 4; ++j)
#pragma unroll
        for (int i = 0; i < 2; ++i) acc[j][i] = (floatx4){0.f, 0.f, 0.f, 0.f};

    const int fr = lane & 15;
    const int fq = lane >> 4;
    const int fx = lane & 7;

    if (kMode) {
        const bf16* bptrK[5];
        int ldsBK[5];
#pragma unroll
        for (int j = 0; j < 5; ++j) {
            const int rloc = wave * 40 + j * 8 + srow;
            const int brel = rloc / 20, pos = rloc % 20;
            bptrK[j] = B + ((long)((bx * 8 + brel) * 20 + pos)) * 512 +
                       ((lane & 7) ^ (pos & 7)) * 8;
            ldsBK[j] = rloc * 64 + (lane & 7) * 8;
        }
        const int bq = wn >> 4;
        for (int c0i = 0; c0i < 8; ++c0i) {
            const int c0 = c0i * 64;
#pragma unroll
            for (int w = 0; w < 5; ++w) {
                const int k0 = w * 512 + c0;
#pragma unroll
                for (int i = 0; i < 2; ++i)
                    __builtin_amdgcn_global_load_lds(
                        (const GLOBAL_AS void*)(aptr[i] + k0),
                        (LDS_AS void*)(As + (wave * 16 + i * 8) * 64), 16, 0, 0);
                if (w == 0) {
#pragma unroll
                    for (int j = 0; j < 5; ++j)
                        __builtin_amdgcn_global_load_lds(
                            (const GLOBAL_AS void*)(bptrK[j] + c0),
                            (LDS_AS void*)(Bs + ldsBK[j]), 16, 0, 0);
                }
                __syncthreads();
#pragma unroll
                for (int kk = 0; kk < 2; ++kk) {
                    bf16x8 af[2], bfr[4];
#pragma unroll
                    for (int im = 0; im < 2; ++im)
                        af[im] = *(const bf16x8*)(As + (wm + im * 16 + fr) * 64 +
                                                  ((((kk << 2) + fq) ^ fx) << 3));
#pragma unroll
                    for (int nt = 0; nt < 4; ++nt) {
                        const int row = (bq + nt) * 20 + fr + w;
                        bfr[nt] = *(const bf16x8*)(
                            Bs + row * 64 +
                            ((((kk << 2) + fq) ^ ((fr + w) & 7)) << 3));
                    }
#pragma unroll
                    for (int nt = 0; nt < 4; ++nt)
#pragma unroll
                        for (int im = 0; im < 2; ++im)
                            acc[nt][im] = __builtin_amdgcn_mfma_f32_16x16x32_bf16(
                                af[im], bfr[nt], acc[nt][im], 0, 0, 0);
                }
                __syncthreads();
            }
        }
    } else {
        const bf16* bptr[4];
#pragma unroll
        for (int i = 0; i < 4; ++i) {
            const int ar = wave * 32 + i * 8 + srow;
            bptr[i] = B + (long)(n0 + ar) * K + gch * 8;
        }
        for (int k0 = 0; k0 < K; k0 += 64) {
#pragma unroll
            for (int i = 0; i < 2; ++i)
                __builtin_amdgcn_global_load_lds(
                    (const GLOBAL_AS void*)(aptr[i] + k0),
                    (LDS_AS void*)(As + (wave * 16 + i * 8) * 64), 16, 0, 0);
#pragma unroll
            for (int i = 0; i < 4; ++i)
                __builtin_amdgcn_global_load_lds(
                    (const GLOBAL_AS void*)(bptr[i] + k0),
                    (LDS_AS void*)(Bs + (wave * 32 + i * 8) * 64), 16, 0, 0);
            __syncthreads();
#pragma unroll
            for (int kk = 0; kk < 2; ++kk) {
                bf16x8 af[2], bfr[4];
#pragma unroll
                for (int im = 0; im < 2; ++im)
                    af[im] = *(const bf16x8*)(As + (wm + im * 16 + fr) * 64 +
                                              ((((kk << 2) + fq) ^ fx) << 3));
#pragma unroll
                for (int in = 0; in < 4; ++in)
                    bfr[in] = *(const bf16x8*)(Bs + (wn + in * 16 + fr) * 64 +
                                               ((((kk << 2) + fq) ^ fx) << 3));
#pragma unroll
                for (int in = 0; in < 4; ++in)
#pragma unroll
                    for (int im = 0; im < 2; ++im)
                        acc[in][im] = __builtin_amdgcn_mfma_f32_16x16x32_bf16(
                            af[im], bfr[in], acc[in][im], 0, 0, 0);
            }
            __syncthreads();
        }
    }
#pragma unroll
    for (int in = 0; in < 4; ++in) {
        const long n = n0 + wn + in * 16 + fr;
#pragma unroll
        for (int im = 0; im < 2; ++im) {
            floatx4 v = acc[in][im];
            const long m = m0 + wm + im * 16 + (fq << 2);
            v.x = fmaxf(v.x, 0.f);
            v.y = fmaxf(v.y, 0.f);
            v.z = fmaxf(v.z, 0.f);
            v.w = fmaxf(v.w, 0.f);
            bf16* Cp = C + (long)bz * cStr + n * 512 + m;
            bf16x4 ov;
            ov[0] = (bf16)v.x;
            ov[1] = (bf16)v.y;
            ov[2] = (bf16)v.z;
            ov[3] = (bf16)v.w;
            *(bf16x4*)Cp = ov;
        }
    }
}

// ---------------- fused attention block (one block per batch b, 512 thr) -----
__global__ __launch_bounds__(512) void k_att(
    const bf16* __restrict__ qh, const bf16* __restrict__ keyh,
    const float* __restrict__ src, const float* __restrict__ dct10,
    const float* __restrict__ lw, const float* __restrict__ lb,
    const float* __restrict__ gia, float* __restrict__ dctin,
    bf16* __restrict__ z0) {
    const int b = blockIdx.x;
    const int t = threadIdx.x;
    __shared__ float BIG[9216];
    __shared__ float WD[2400];
    __shared__ float D[350];
    __shared__ float L[1920];
    __shared__ float dinS[960];
    __shared__ float sS[64];
    __shared__ float awS[64];

    {
        const int g = t >> 3, lane = t & 7;
        const int h = g >> 4, tt = g & 15;
        const bf16* q = qh + ((long)h * 256 + b) * 512 + lane * 64;
        const bf16* kr = keyh + (long)h * 2097152 + ((long)b * 16 + tt) * 512 + lane * 64;
        float p = 0.f;
#pragma unroll
        for (int i = 0; i < 8; ++i) {
            const bf16x8 qv = *(const bf16x8*)(q + i * 8);
            const bf16x8 kv = *(const bf16x8*)(kr + i * 8);
#pragma unroll
            for (int j = 0; j < 8; ++j) p = fmaf((float)qv[j], (float)kv[j], p);
        }
        p += __shfl_down(p, 4, 8);
        p += __shfl_down(p, 2, 8);
        p += __shfl_down(p, 1, 8);
        if (lane == 0) sS[g] = p + 1e-15f;
    }
    for (int i = t; i < 2400; i += 512) WD[i] = src[(long)b * 2400 + i];
    for (int i = t; i < 350; i += 512) D[i] = dct10[i];
    __syncthreads();
    if (t < 4) {
        float s = 0.f;
#pragma unroll
        for (int k = 0; k < 16; ++k) s += sS[t * 16 + k];
        const float inv = 1.f / s;
#pragma unroll
        for (int k = 0; k < 16; ++k) awS[t * 16 + k] = sS[t * 16 + k] * inv;
    }
    __syncthreads();
    // sv windows: thread t<480 owns (f=t/10, d=t%10); D row in registers
    if (t < 480) {
        const int f = t / 10, d = t % 10;
        float dreg[35];
#pragma unroll
        for (int v = 0; v < 35; ++v) dreg[v] = D[d * 35 + v];
#pragma unroll 2
        for (int n = 0; n < 16; ++n) {
            float acc = 0.f;
#pragma unroll
            for (int v = 0; v < 35; ++v)
                acc = fmaf(dreg[v], WD[(n + v) * 48 + f], acc);
            BIG[n * 480 + t] = acc;
        }
        // dctin cols 0..9 (gather rows 40..49, last row repeated)
        float acc = 0.f;
#pragma unroll
        for (int v = 0; v < 10; ++v)
            acc = fmaf(dreg[v], WD[(40 + v) * 48 + f], acc);
        float cs = 0.f;
#pragma unroll
        for (int v = 10; v < 35; ++v) cs += dreg[v];
        acc = fmaf(cs, WD[49 * 48 + f], acc);
        dinS[f * 20 + d] = acc;
        dctin[(long)b * 960 + f * 20 + d] = acc;
    }
    __syncthreads();
    for (int p = 0; p < 4; ++p) {
        const int idx = t + p * 512;
        if (idx < 1920) {
            const int h = idx / 480, j = idx % 480;
            float acc = 0.f;
#pragma unroll
            for (int k = 0; k < 16; ++k)
                acc = fmaf(awS[h * 16 + k], BIG[k * 480 + j], acc);
            L[idx] = acc;
        }
    }
    __syncthreads();
    for (int i = t; i < 9216; i += 512) BIG[i] = lw[i];
    for (int i = t; i < 2304; i += 512) WD[i] = gia[i];
    __syncthreads();
    if (t < 480) {
        const int n = t / 10, d = t % 10;
        float acc = lb[n];
#pragma unroll
        for (int h = 0; h < 4; ++h)
#pragma unroll
            for (int f = 0; f < 48; ++f)
                acc = fmaf(BIG[n * 192 + h * 48 + f], L[h * 480 + f * 10 + d], acc);
        dinS[n * 20 + 10 + d] = acc;
        dctin[(long)b * 960 + n * 20 + 10 + d] = acc;
    }
    __syncthreads();
    for (int p = 0; p < 2; ++p) {
        const int idx = t + p * 512;
        if (idx < 960) {
            const int n = idx / 20, d = idx % 20;
            float acc = 0.f;
#pragma unroll
            for (int m = 0; m < 48; ++m)
                acc = fmaf(WD[n * 48 + m], dinS[m * 20 + d], acc);
            z0[((long)b * 48 + n) * 64 + d] = (bf16)acc;
        }
    }
    for (int i = t; i < 2112; i += 512) {
        const int n = i / 44, c = 20 + i % 44;
        z0[((long)b * 48 + n) * 64 + c] = (bf16)0.f;
    }
}

// ---------------- GCN mega-kernel (fragment-W + packed epilogue) -------------
template <bool TOUT, int S>
__device__ __forceinline__ void gcn_matmul3(
    const bf16* __restrict__ zSrc, const bf16* __restrict__ Wf,
    const float* __restrict__ bias, const bf16* __restrict__ resT,
    bf16* __restrict__ outS, const int wave, const int lane) {
    const int fr = lane & 15, fq = lane >> 4;
    const int f0 = wave * 32;
    floatx4 acc[3][2];
#pragma unroll
    for (int it = 0; it < 3; ++it)
#pragma unroll
        for (int jt = 0; jt < 2; ++jt) acc[it][jt] = (floatx4){0.f, 0.f, 0.f, 0.f};
    const bf16* wp = Wf + (long)wave * (S * 1024) + (lane << 3);
    bf16x8 w0[4], w1[4];
    constexpr int PRE = (S < 3) ? S : 3;
#pragma unroll
    for (int s = 0; s < PRE; ++s) {
        w0[s] = *(const bf16x8*)(wp + s * 1024);
        w1[s] = *(const bf16x8*)(wp + s * 1024 + 512);
    }
#pragma unroll
    for (int s = 0; s < S; ++s) {
        bf16x8 af[3];
#pragma unroll
        for (int it = 0; it < 3; ++it)
            af[it] = *(const bf16x8*)(zSrc + (it * 16 + fr) * 520 + s * 32 + fq * 8);
        if (s + 3 < S) {
            const int ns = (s + 3) & 3;
            w0[ns] = *(const bf16x8*)(wp + (s + 3) * 1024);
            w1[ns] = *(const bf16x8*)(wp + (s + 3) * 1024 + 512);
        }
        const int sl = s & 3;
#pragma unroll
        for (int it = 0; it < 3; ++it) {
            acc[it][0] = __builtin_amdgcn_mfma_f32_16x16x32_bf16(af[it], w0[sl],
                                                                acc[it][0], 0, 0, 0);
            acc[it][1] = __builtin_amdgcn_mfma_f32_16x16x32_bf16(af[it], w1[sl],
                                                                acc[it][1], 0, 0, 0);
        }
    }
#pragma unroll
    for (int jt = 0; jt < 2; ++jt) {
        const int f = f0 + jt * 16 + fr;
        const float bv = bias[f];
#pragma unroll
        for (int it = 0; it < 3; ++it) {
            const int ir0 = it * 16 + fq * 4;
            float v[4];
#pragma unroll
            for (int r = 0; r < 4; ++r)
                v[r] = tanh_fast((acc[it][jt][r] + bv) * BN_SCALE_F);
            if (resT) {
                const bf16x4 rv = *(const bf16x4*)(resT + f * 48 + ir0);
#pragma unroll
                for (int r = 0; r < 4; ++r) v[r] += (float)rv[r];
            }
            if (TOUT) {
                bf16x4 ov;
#pragma unroll
                for (int r = 0; r < 4; ++r) ov[r] = (bf16)v[r];
                *(bf16x4*)(outS + f * 48 + ir0) = ov;
            } else {
#pragma unroll
                for (int r = 0; r < 4; ++r)
                    outS[(ir0 + r) * 520 + f] = (bf16)v[r];
            }
        }
    }
}

__device__ __forceinline__ void gcn_attmul2(const bf16* __restrict__ gA,
                                            const bf16* __restrict__ YinT,
                                            bf16* __restrict__ zOut,
                                            const int wave, const int lane) {
    const int fr = lane & 15, fq = lane >> 4;
    const int f0 = wave * 32;
    floatx4 acc[3][2];
#pragma unroll
    for (int it = 0; it < 3; ++it)
#pragma unroll
        for (int jt = 0; jt < 2; ++jt) acc[it][jt] = (floatx4){0.f, 0.f, 0.f, 0.f};
    bf16x8 af0[3], af1[3], bv0[2], bv1[2];
#pragma unroll
    for (int it = 0; it < 3; ++it) {
        af0[it] = *(const bf16x8*)(gA + (it * 16 + fr) * 64 + fq * 8);
        af1[it] = *(const bf16x8*)(gA + (it * 16 + fr) * 64 + 32 + fq * 8);
    }
#pragma unroll
    for (int jt = 0; jt < 2; ++jt) {
        const int f = f0 + jt * 16 + fr;
        bv0[jt] = *(const bf16x8*)(YinT + f * 48 + fq * 8);
        bv1[jt] = *(const bf16x8*)(YinT + f * 48 + 32 + fq * 8);
    }
#pragma unroll
    for (int it = 0; it < 3; ++it)
#pragma unroll
        for (int jt = 0; jt < 2; ++jt) {
            acc[it][jt] = __builtin_amdgcn_mfma_f32_16x16x32_bf16(af0[it], bv0[jt],
                                                                 acc[it][jt], 0, 0, 0);
            acc[it][jt] = __builtin_amdgcn_mfma_f32_16x16x32_bf16(af1[it], bv1[jt],
                                                                 acc[it][jt], 0, 0, 0);
        }
#pragma unroll
    for (int jt = 0; jt < 2; ++jt) {
        const int f = f0 + jt * 16 + fr;
#pragma unroll
        for (int it = 0; it < 3; ++it)
#pragma unroll
            for (int r = 0; r < 4; ++r)
                zOut[(it * 16 + fq * 4 + r) * 520 + f] = (bf16)acc[it][jt][r];
    }
}

__global__ __launch_bounds__(1024) void k_gcn(
    const bf16* __restrict__ z0, const bf16* __restrict__ giwF,
    const float* __restrict__ gib, const bf16* __restrict__ gbwF,
    const bf16* __restrict__ gbaP, const float* __restrict__ gbb,
    const float* __restrict__ goa, const bf16* __restrict__ gowT,
    const float* __restrict__ gob, const float* __restrict__ dctin,
    const float* __restrict__ dct10, float* __restrict__ out) {
    const int b = blockIdx.x;
    const int t = threadIdx.x;
    const int wave = t >> 6, lane = t & 63;
    // yaS: transposed Y^T[512][48] (+16 zero tail) OR final normal [48][520]
    __shared__ __align__(16) bf16 yaS[24976];
    __shared__ __align__(16) bf16 ybS[24592];
    __shared__ __align__(16) bf16 zS[48 * 520];

    if (t < 384) {
        const int r = t >> 3, c = t & 7;
        *(bf16x8*)(zS + r * 520 + c * 8) =
            *(const bf16x8*)(z0 + ((long)b * 48 + r) * 64 + c * 8);
    } else if (t < 400) {
        yaS[24576 + (t - 384)] = (bf16)0.f;
    } else if (t < 416) {
        ybS[24576 + (t - 400)] = (bf16)0.f;
    }
    __syncthreads();
    gcn_matmul3<true, 2>(zS, giwF, gib, nullptr, yaS, wave, lane);
    __syncthreads();

#pragma unroll
    for (int l = 0; l < 4; ++l) {
        const bf16* YinT = (l == 0 || l == 3) ? yaS : ybS;
        gcn_attmul2(gbaP + l * 3072, YinT, zS, wave, lane);
        __syncthreads();
        const bf16* Res = (l == 1) ? yaS : (l == 3 ? ybS : nullptr);
        if (l < 3)
            gcn_matmul3<true, 16>(zS, gbwF + (long)l * 262144, gbb + l * 512,
                                  Res, (l < 2) ? ybS : yaS, wave, lane);
        else
            gcn_matmul3<false, 16>(zS, gbwF + 3L * 262144, gbb + 3 * 512, Res,
                                   yaS, wave, lane);
        __syncthreads();
    }
    // ---- gc_out + iDCT (final Y = yaS, normal [48][520] layout) ----
    float* T2 = (float*)ybS;             // 960 f32
    float* dS = ((float*)ybS) + 960;     // 960 f32
    float* goaS = ((float*)ybS) + 1920;  // 2304 f32
    float* Df = ((float*)ybS) + 4224;    // 350 f32
    if (t < 384) {
        // 6 waves: T2[48][20] = Yfin(48x512) x gow(512x20) via MFMA
        const int fr2 = lane & 15, fq2 = lane >> 4;
        const int it = wave >> 1, jt = wave & 1;
        floatx4 accT = (floatx4){0.f, 0.f, 0.f, 0.f};
        const bf16* ap = yaS + (it * 16 + fr2) * 520 + fq2 * 8;
        const bf16* gp = gowT + (long)(jt * 16 + fr2) * 512 + fq2 * 8;
        for (int k0 = 0; k0 < 512; k0 += 32) {
            const bf16x8 av = *(const bf16x8*)(ap + k0);
            const bf16x8 gv = *(const bf16x8*)(gp + k0);
            accT = __builtin_amdgcn_mfma_f32_16x16x32_bf16(av, gv, accT, 0, 0, 0);
        }
        const int d = jt * 16 + fr2;
        if (d < 20) {
#pragma unroll
            for (int r = 0; r < 4; ++r) {
                const int m = it * 16 + fq2 * 4 + r;
                T2[m * 20 + d] = accT[r];
            }
        }
    } else {
        for (int i = t - 384; i < 2304; i += 640) goaS[i] = goa[i];
        for (int i = t - 384; i < 350; i += 640) Df[i] = dct10[i];
    }
    __syncthreads();
    if (t < 960) {
        const int n = t / 20, d = t % 20;
        float acc = gob[d] + dctin[(long)b * 960 + t];
#pragma unroll
        for (int m = 0; m < 48; ++m)
            acc = fmaf(goaS[n * 48 + m], T2[m * 20 + d], acc);
        dS[t] = acc;
    }
    __syncthreads();
    for (int e = t; e < 1680; e += 1024) {
        const int v = e / 48, n = e % 48;
        float acc = 0.f;
#pragma unroll
        for (int d = 0; d < 10; ++d)
            acc = fmaf(Df[d * 35 + v], dS[n * 20 + d], acc);
        out[(long)b * 1680 + e] = acc;
    }
}

// ---------------------------------------------------------------------------
// Workspace (BYTE offsets). keyh bf16 (16.8 MB) aliases WS_T; z0 at WS_T+17MB.
// gowT/gbaP live in the (otherwise unused) WS_PAD0 region.
// ---------------------------------------------------------------------------
static constexpr size_t WS_DCT10 = 0;
static constexpr size_t WS_ATTW = 1536;
static constexpr size_t WS_QH = WS_ATTW + 65536;
static constexpr size_t WS_DCTIN = WS_QH + 2097152;
static constexpr size_t WS_DCTOUT = WS_DCTIN + 983040;
static constexpr size_t WS_SRCVAL = WS_DCTOUT + 983040;
static constexpr size_t WS_PAD0 = WS_SRCVAL + 7864320;
static constexpr size_t WS_GOWT = WS_PAD0;                  // 32*512*2 = 32768
static constexpr size_t WS_GBAP = WS_PAD0 + 32768;          // 4*48*64*2 = 24576
static constexpr size_t WS_SRCBF = WS_PAD0 + 8388608;
static constexpr size_t WS_W1TQ = WS_SRCBF + 1229824;
static constexpr size_t WS_W1TK = WS_W1TQ + 1310720;
static constexpr size_t WS_W2TQ = WS_W1TK + 1310720;
static constexpr size_t WS_W2TK = WS_W2TQ + 10485760;
static constexpr size_t WS_GBWT = WS_W2TK + 10485760;
static constexpr size_t WS_R1K = WS_GBWT + 2097152;
static constexpr size_t WS_R1Q = WS_R1K + 20971520;
static constexpr size_t WS_T = WS_R1Q + 5242880;
static constexpr size_t WS_GIWP = WS_T + 50331648;
static constexpr size_t WS_KEYH = WS_T;
static constexpr size_t WS_Z0 = WS_T + 17825792;

extern "C" void kernel_launch(void* const* d_in, const int* in_sizes, int n_in,
                              void* d_out, int out_size, void* d_ws,
                              size_t ws_size, hipStream_t stream) {
    const float* src = (const float*)d_in[0];
    const float* cq1 = (const float*)d_in[1];
    const float* cq2 = (const float*)d_in[2];
    const float* ck1 = (const float*)d_in[3];
    const float* ck2 = (const float*)d_in[4];
    const float* lw = (const float*)d_in[5];
    const float* lb = (const float*)d_in[6];
    const float* giw = (const float*)d_in[7];
    const float* gia = (const float*)d_in[8];
    const float* gib = (const float*)d_in[9];
    const float* gbw = (const float*)d_in[10];
    const float* gba = (const float*)d_in[11];
    const float* gbb = (const float*)d_in[12];
    const float* gow = (const float*)d_in[13];
    const float* goa = (const float*)d_in[14];
    const float* gob = (const float*)d_in[15];
    float* out = (float*)d_out;
    char* ws = (char*)d_ws;

    float* dct10 = (float*)(ws + WS_DCT10);
    bf16* qh = (bf16*)(ws + WS_QH);
    float* dctin = (float*)(ws + WS_DCTIN);
    bf16* keyh = (bf16*)(ws + WS_KEYH);
    bf16* srcbf = (bf16*)(ws + WS_SRCBF);
    bf16* w1tq = (bf16*)(ws + WS_W1TQ);
    bf16* w1tk = (bf16*)(ws + WS_W1TK);
    bf16* w2tq = (bf16*)(ws + WS_W2TQ);
    bf16* w2tk = (bf16*)(ws + WS_W2TK);
    bf16* gbwF = (bf16*)(ws + WS_GBWT);
    bf16* r1k = (bf16*)(ws + WS_R1K);
    bf16* r1q = (bf16*)(ws + WS_R1Q);
    bf16* giwF = (bf16*)(ws + WS_GIWP);
    bf16* gowT = (bf16*)(ws + WS_GOWT);
    bf16* gbaP = (bf16*)(ws + WS_GBAP);
    bf16* z0 = (bf16*)(ws + WS_Z0);

    // 1. all prep in one dispatch: vectorized, 3223 blocks
    k_prep<<<3223, 256, 0, stream>>>(src, cq1, ck1, cq2, ck2, gbw, giw, gow,
                                     gba, dct10, srcbf, w1tq, w1tk, w2tq,
                                     w2tk, gbwF, giwF, gowT, gbaP);

    // 2. conv1 K+Q: 64x128 tiles, 1600 uniform blocks
    k_conv1<<<1600, 256, 0, stream>>>(w1tk, w1tq, srcbf, r1k, r1q);

    // 3. conv2 K+Q: window-dedup B staging, 1088 blocks (frozen at r9)
    k_conv2<<<1088, 256, 0, stream>>>(w2tk, r1k, keyh, w2tq, r1q, qh);

    // 4. fused attention block -> dctin (fp32), z0 (bf16)  [512 thr, no spill]
    k_att<<<256, 512, 0, stream>>>(qh, keyh, src, dct10, lw, lb, gia, dctin, z0);

    // 5. whole GCN in one dispatch (fragment-W + packed epilogue)
    k_gcn<<<256, 1024, 0, stream>>>(z0, giwF, gib, gbwF, gbaP, gbb, goa, gowT,
                                    gob, dctin, dct10, out);
}